// Round 3
// baseline (88.013 us; speedup 1.0000x reference)
//
#include <hip/hip_runtime.h>

// AttEncoder fused: per-channel conv1d encoder + channel attention (C=4).
// Key identity: w[b,i,j,t] = x_i(t)^T M_ij x_j(t), M_ij precomputed from W.
// Only the v-conv is done at full N=512; q/k convs are folded into M (16x16).
//
// R2: k2 latency-bound (occ 20%) -> FC 64->16, grid 512->2048.  87->65 us.
// R3: k2 was register-starved (VGPR_Count=48 < 64 live floats for xr ->
//     remat/spill across f-loop). __launch_bounds__(256,1) lets the allocator
//     keep xr resident (~112 VGPR, still 4 waves/SIMD). Nontemporal output
//     stores (write-once data, keep 131 MB out of L2).

#define BB 4
#define CC 4
#define LL 32000
#define KK 16
#define ST 8
#define NN 512
#define TT 3999      // (LL-KK)/ST + 1
#define F3 1536
#define FC 16        // f-chunk per block in k2

// ---------------- k0: M[i][j][k][k2] = sum_f Wq[i,f,k] * Wk[j,f,k2] ----------
// Wq[c,f,k] = W[(c*F3 + NN  + f)*KK + k]
// Wk[c,f,k] = W[(c*F3 + 0   + f)*KK + k]
__global__ __launch_bounds__(256) void k0_M(const float* __restrict__ W,
                                            float* __restrict__ M) {
  const int i = blockIdx.x >> 2, j = blockIdx.x & 3;
  __shared__ float wq[NN * KK];   // 32 KB
  __shared__ float wk[NN * KK];   // 32 KB
  const int baseq = (i * F3 + NN) * KK;
  const int basek = (j * F3) * KK;
  for (int idx = threadIdx.x; idx < NN * KK; idx += 256) {
    wq[idx] = W[baseq + idx];
    wk[idx] = W[basek + idx];
  }
  __syncthreads();
  const int k = threadIdx.x >> 4, k2 = threadIdx.x & 15;
  float acc = 0.f;
  for (int f = 0; f < NN; ++f)
    acc = fmaf(wq[f * KK + k], wk[f * KK + k2], acc);
  M[((i * 4 + j) * 16 + k) * 16 + k2] = acc;
}

// ---------------- k1: A[b][i][j][t] = 0.5*(softmax_j(w) + delta_ij) ----------
template <int I>
__device__ __forceinline__ void k1_row(const float xr[4][16],
                                       const float* __restrict__ M,
                                       float* __restrict__ A, int bb, int t) {
  float w[4];
#pragma unroll
  for (int j = 0; j < 4; ++j) {
    const float* Mp = M + (I * 4 + j) * 256;
    float acc = 0.f;
#pragma unroll
    for (int k = 0; k < 16; ++k) {
      float y = 0.f;
#pragma unroll
      for (int k2 = 0; k2 < 16; ++k2)
        y = fmaf(Mp[k * 16 + k2], xr[j][k2], y);
      acc = fmaf(xr[I][k], y, acc);
    }
    w[j] = acc;
  }
  const float m = fmaxf(fmaxf(w[0], w[1]), fmaxf(w[2], w[3]));
  const float e0 = __expf(w[0] - m), e1 = __expf(w[1] - m);
  const float e2 = __expf(w[2] - m), e3 = __expf(w[3] - m);
  const float inv = 0.5f / (e0 + e1 + e2 + e3);
  float av0 = e0 * inv, av1 = e1 * inv, av2 = e2 * inv, av3 = e3 * inv;
  if (I == 0) av0 += 0.5f;
  if (I == 1) av1 += 0.5f;
  if (I == 2) av2 += 0.5f;
  if (I == 3) av3 += 0.5f;
  float* Ap = A + ((bb * 4 + I) * 4) * TT + t;
  Ap[0 * TT] = av0;
  Ap[1 * TT] = av1;
  Ap[2 * TT] = av2;
  Ap[3 * TT] = av3;
}

// block = 256 threads = 4 waves; each wave handles one query row i for the
// same 64 t values (uniform branch per wave, no divergence).
__global__ __launch_bounds__(256, 1) void k1_A(const float* __restrict__ x,
                                               const float* __restrict__ M,
                                               float* __restrict__ A) {
  const int bb = blockIdx.y;
  const int lane = threadIdx.x & 63;
  const int wv = threadIdx.x >> 6;
  const int t = blockIdx.x * 64 + lane;
  if (t >= TT) return;
  float xr[4][16];
#pragma unroll
  for (int c = 0; c < 4; ++c) {
    const float* xp = x + (bb * CC + c) * LL + t * ST;
#pragma unroll
    for (int k4 = 0; k4 < 16; k4 += 4) {
      const float4 v4 = *reinterpret_cast<const float4*>(xp + k4);
      xr[c][k4 + 0] = v4.x;
      xr[c][k4 + 1] = v4.y;
      xr[c][k4 + 2] = v4.z;
      xr[c][k4 + 3] = v4.w;
    }
  }
  if (wv == 0)      k1_row<0>(xr, M, A, bb, t);
  else if (wv == 1) k1_row<1>(xr, M, A, bb, t);
  else if (wv == 2) k1_row<2>(xr, M, A, bb, t);
  else              k1_row<3>(xr, M, A, bb, t);
}

// ---------------- k2: v-conv + mix + store ----------------------------------
// out[b,i,f,t] = sum_j A[b,i,j,t] * v[b,j,f,t],  v[c,f,t] = Wv[c,f,:] . x_c(t)
// Wv[c,f,k] = W[(c*F3 + 2*NN + f)*KK + k]   (uniform index -> scalar loads)
__global__ __launch_bounds__(256, 1) void k2_out(const float* __restrict__ x,
                                                 const float* __restrict__ W,
                                                 const float* __restrict__ A,
                                                 float* __restrict__ out) {
  const int bb = blockIdx.x >> 4;
  const int t = (blockIdx.x & 15) * 256 + (int)threadIdx.x;
  const int f0 = blockIdx.y * FC;
  if (t >= TT) return;
  float xr[4][16];
#pragma unroll
  for (int c = 0; c < 4; ++c) {
    const float* xp = x + (bb * CC + c) * LL + t * ST;
#pragma unroll
    for (int k4 = 0; k4 < 16; k4 += 4) {
      const float4 v4 = *reinterpret_cast<const float4*>(xp + k4);
      xr[c][k4 + 0] = v4.x;
      xr[c][k4 + 1] = v4.y;
      xr[c][k4 + 2] = v4.z;
      xr[c][k4 + 3] = v4.w;
    }
  }
  float a[4][4];
#pragma unroll
  for (int i = 0; i < 4; ++i)
#pragma unroll
    for (int j = 0; j < 4; ++j)
      a[i][j] = A[((bb * 4 + i) * 4 + j) * TT + t];

#pragma unroll 4
  for (int f = 0; f < FC; ++f) {
    const int fg = f0 + f;
    const float* w0 = W + (0 * F3 + 2 * NN + fg) * KK;
    const float* w1 = W + (1 * F3 + 2 * NN + fg) * KK;
    const float* w2 = W + (2 * F3 + 2 * NN + fg) * KK;
    const float* w3 = W + (3 * F3 + 2 * NN + fg) * KK;
    float v0 = 0.f, v1 = 0.f, v2 = 0.f, v3 = 0.f;
#pragma unroll
    for (int k = 0; k < 16; ++k) {
      v0 = fmaf(w0[k], xr[0][k], v0);
      v1 = fmaf(w1[k], xr[1][k], v1);
      v2 = fmaf(w2[k], xr[2][k], v2);
      v3 = fmaf(w3[k], xr[3][k], v3);
    }
#pragma unroll
    for (int i = 0; i < 4; ++i) {
      const float o =
          fmaf(a[i][3], v3, fmaf(a[i][2], v2, fmaf(a[i][1], v1, a[i][0] * v0)));
      __builtin_nontemporal_store(o, &out[((bb * 4 + i) * NN + fg) * TT + t]);
    }
  }
}

extern "C" void kernel_launch(void* const* d_in, const int* in_sizes, int n_in,
                              void* d_out, int out_size, void* d_ws,
                              size_t ws_size, hipStream_t stream) {
  const float* x = (const float*)d_in[0];   // [B, C, L] fp32
  const float* W = (const float*)d_in[1];   // [C, F3, 1, K] fp32
  float* out = (float*)d_out;               // [B, C, N, T] fp32
  float* Mws = (float*)d_ws;                // 4096 floats
  float* Aws = Mws + 4 * 4 * 16 * 16;       // B*4*4*T floats (~1 MB)

  hipLaunchKernelGGL(k0_M, dim3(16), dim3(256), 0, stream, W, Mws);
  hipLaunchKernelGGL(k1_A, dim3(63, BB), dim3(256), 0, stream, x, Mws, Aws);
  hipLaunchKernelGGL(k2_out, dim3(64, 32), dim3(256), 0, stream, x, W, Aws, out);
}

// Round 4
// 60.109 us; speedup vs baseline: 1.4642x; 1.4642x over previous
//
#include <hip/hip_runtime.h>

// AttEncoder fused: per-channel conv1d encoder + channel attention (C=4).
// Key identity: w[b,i,j,t] = x_i(t)^T M_ij x_j(t), M_ij precomputed from W.
// Only the v-conv is done at full N=512; q/k convs are folded into M (16x16).
//
// R2: k2 latency-bound (occ 20%) -> FC 64->16, grid 512->2048.  87->65 us.
// R3 FAILED: __launch_bounds__(256,1) = min 1 wave/EU -> VGPR cap 512 ->
//     1 block/CU -> no latency hiding. 65->88 us. (NT stores confounded in.)
// R4: __launch_bounds__(256,4): VGPR cap 128 (xr[64]+a[16]+work fits, W rows
//     are wave-uniform s_loads) AND 4 waves/SIMD. Plain stores. A relayout
//     [b][t][i][j] -> k1 float4 stores, k2 4x float4 a-loads.

#define BB 4
#define CC 4
#define LL 32000
#define KK 16
#define ST 8
#define NN 512
#define TT 3999      // (LL-KK)/ST + 1
#define F3 1536
#define FC 16        // f-chunk per block in k2

// ---------------- k0: M[i][j][k][k2] = sum_f Wq[i,f,k] * Wk[j,f,k2] ----------
// Wq[c,f,k] = W[(c*F3 + NN  + f)*KK + k]
// Wk[c,f,k] = W[(c*F3 + 0   + f)*KK + k]
__global__ __launch_bounds__(256) void k0_M(const float* __restrict__ W,
                                            float* __restrict__ M) {
  const int i = blockIdx.x >> 2, j = blockIdx.x & 3;
  __shared__ float wq[NN * KK];   // 32 KB
  __shared__ float wk[NN * KK];   // 32 KB
  const int baseq = (i * F3 + NN) * KK;
  const int basek = (j * F3) * KK;
  for (int idx = threadIdx.x; idx < NN * KK; idx += 256) {
    wq[idx] = W[baseq + idx];
    wk[idx] = W[basek + idx];
  }
  __syncthreads();
  const int k = threadIdx.x >> 4, k2 = threadIdx.x & 15;
  float acc = 0.f;
  for (int f = 0; f < NN; ++f)
    acc = fmaf(wq[f * KK + k], wk[f * KK + k2], acc);
  M[((i * 4 + j) * 16 + k) * 16 + k2] = acc;
}

// ---------------- k1: A[b][t][i][j] = 0.5*(softmax_j(w) + delta_ij) ---------
template <int I>
__device__ __forceinline__ void k1_row(const float xr[4][16],
                                       const float* __restrict__ M,
                                       float* __restrict__ A, int bb, int t) {
  float w[4];
#pragma unroll
  for (int j = 0; j < 4; ++j) {
    const float* Mp = M + (I * 4 + j) * 256;
    float acc = 0.f;
#pragma unroll
    for (int k = 0; k < 16; ++k) {
      float y = 0.f;
#pragma unroll
      for (int k2 = 0; k2 < 16; ++k2)
        y = fmaf(Mp[k * 16 + k2], xr[j][k2], y);
      acc = fmaf(xr[I][k], y, acc);
    }
    w[j] = acc;
  }
  const float m = fmaxf(fmaxf(w[0], w[1]), fmaxf(w[2], w[3]));
  const float e0 = __expf(w[0] - m), e1 = __expf(w[1] - m);
  const float e2 = __expf(w[2] - m), e3 = __expf(w[3] - m);
  const float inv = 0.5f / (e0 + e1 + e2 + e3);
  float4 av;
  av.x = e0 * inv;
  av.y = e1 * inv;
  av.z = e2 * inv;
  av.w = e3 * inv;
  if (I == 0) av.x += 0.5f;
  if (I == 1) av.y += 0.5f;
  if (I == 2) av.z += 0.5f;
  if (I == 3) av.w += 0.5f;
  // A[b][t][i][j], one float4 per (b,t,i)
  *reinterpret_cast<float4*>(A + ((bb * TT + t) * 4 + I) * 4) = av;
}

// block = 256 threads = 4 waves; each wave handles one query row i for the
// same 64 t values (uniform branch per wave, no divergence).
__global__ __launch_bounds__(256, 4) void k1_A(const float* __restrict__ x,
                                               const float* __restrict__ M,
                                               float* __restrict__ A) {
  const int bb = blockIdx.y;
  const int lane = threadIdx.x & 63;
  const int wv = threadIdx.x >> 6;
  const int t = blockIdx.x * 64 + lane;
  if (t >= TT) return;
  float xr[4][16];
#pragma unroll
  for (int c = 0; c < 4; ++c) {
    const float* xp = x + (bb * CC + c) * LL + t * ST;
#pragma unroll
    for (int k4 = 0; k4 < 16; k4 += 4) {
      const float4 v4 = *reinterpret_cast<const float4*>(xp + k4);
      xr[c][k4 + 0] = v4.x;
      xr[c][k4 + 1] = v4.y;
      xr[c][k4 + 2] = v4.z;
      xr[c][k4 + 3] = v4.w;
    }
  }
  if (wv == 0)      k1_row<0>(xr, M, A, bb, t);
  else if (wv == 1) k1_row<1>(xr, M, A, bb, t);
  else if (wv == 2) k1_row<2>(xr, M, A, bb, t);
  else              k1_row<3>(xr, M, A, bb, t);
}

// ---------------- k2: v-conv + mix + store ----------------------------------
// out[b,i,f,t] = sum_j A[b,t,i,j] * v[b,j,f,t],  v[c,f,t] = Wv[c,f,:] . x_c(t)
// Wv[c,f,k] = W[(c*F3 + 2*NN + f)*KK + k]   (wave-uniform index -> s_load)
__global__ __launch_bounds__(256, 4) void k2_out(const float* __restrict__ x,
                                                 const float* __restrict__ W,
                                                 const float* __restrict__ A,
                                                 float* __restrict__ out) {
  const int bb = blockIdx.x >> 4;
  const int t = (blockIdx.x & 15) * 256 + (int)threadIdx.x;
  const int f0 = blockIdx.y * FC;
  if (t >= TT) return;
  float xr[4][16];
#pragma unroll
  for (int c = 0; c < 4; ++c) {
    const float* xp = x + (bb * CC + c) * LL + t * ST;
#pragma unroll
    for (int k4 = 0; k4 < 16; k4 += 4) {
      const float4 v4 = *reinterpret_cast<const float4*>(xp + k4);
      xr[c][k4 + 0] = v4.x;
      xr[c][k4 + 1] = v4.y;
      xr[c][k4 + 2] = v4.z;
      xr[c][k4 + 3] = v4.w;
    }
  }
  float4 a[4];
  {
    const float4* ap = reinterpret_cast<const float4*>(A + (bb * TT + t) * 16);
#pragma unroll
    for (int i = 0; i < 4; ++i) a[i] = ap[i];
  }

#pragma unroll 2
  for (int f = 0; f < FC; ++f) {
    const int fg = f0 + f;
    const float* w0 = W + (0 * F3 + 2 * NN + fg) * KK;
    const float* w1 = W + (1 * F3 + 2 * NN + fg) * KK;
    const float* w2 = W + (2 * F3 + 2 * NN + fg) * KK;
    const float* w3 = W + (3 * F3 + 2 * NN + fg) * KK;
    float v0 = 0.f, v1 = 0.f, v2 = 0.f, v3 = 0.f;
#pragma unroll
    for (int k = 0; k < 16; ++k) {
      v0 = fmaf(w0[k], xr[0][k], v0);
      v1 = fmaf(w1[k], xr[1][k], v1);
      v2 = fmaf(w2[k], xr[2][k], v2);
      v3 = fmaf(w3[k], xr[3][k], v3);
    }
#pragma unroll
    for (int i = 0; i < 4; ++i) {
      const float o =
          fmaf(a[i].w, v3, fmaf(a[i].z, v2, fmaf(a[i].y, v1, a[i].x * v0)));
      out[((bb * 4 + i) * NN + fg) * TT + t] = o;
    }
  }
}

extern "C" void kernel_launch(void* const* d_in, const int* in_sizes, int n_in,
                              void* d_out, int out_size, void* d_ws,
                              size_t ws_size, hipStream_t stream) {
  const float* x = (const float*)d_in[0];   // [B, C, L] fp32
  const float* W = (const float*)d_in[1];   // [C, F3, 1, K] fp32
  float* out = (float*)d_out;               // [B, C, N, T] fp32
  float* Mws = (float*)d_ws;                // 4096 floats
  float* Aws = Mws + 4 * 4 * 16 * 16;       // B*T*4*4 floats (~1 MB)

  hipLaunchKernelGGL(k0_M, dim3(16), dim3(256), 0, stream, W, Mws);
  hipLaunchKernelGGL(k1_A, dim3(63, BB), dim3(256), 0, stream, x, Mws, Aws);
  hipLaunchKernelGGL(k2_out, dim3(64, 32), dim3(256), 0, stream, x, W, Aws, out);
}

// Round 5
// 57.909 us; speedup vs baseline: 1.5199x; 1.0380x over previous
//
#include <hip/hip_runtime.h>

// AttEncoder fused: per-channel conv1d encoder + channel attention (C=4).
// Key identity: w[b,i,j,t] = x_i(t)^T M_ij x_j(t), M_ij precomputed from W.
// Only the v-conv is done at full N=512; q/k convs are folded into M (16x16).
//
// R2: k2 latency-bound (occ 20%) -> FC 64->16, grid 512->2048.  87->65 us.
// R3 FAILED: __launch_bounds__(256,1) = 1 block/CU, no latency hiding. 88 us.
// R4: (256,4) VGPR cap 128 + A[b][t][i][j] float4. 60 us. TLP sweep (R2 32
//     waves/CU vs R4 16 waves/CU) barely moved k2 -> not latency/issue bound.
// R5: store-path theory: k2 writes 131 MB at only ~2.8 TB/s (fill kernel does
//     6.9). Blocks covered 256 t -> 1 KB contiguous runs per (i,f) row at
//     16 KB strides = HBM row-locality worst case. Fix: 1024-thread blocks
//     (t-range 1024 -> 4 KB runs), FC=32, grid 256 = 1 block/CU.

#define BB 4
#define CC 4
#define LL 32000
#define KK 16
#define ST 8
#define NN 512
#define TT 3999      // (LL-KK)/ST + 1
#define F3 1536
#define FC 32        // f-chunk per block in k2 (R5: was 16)

// ---------------- k0: M[i][j][k][k2] = sum_f Wq[i,f,k] * Wk[j,f,k2] ----------
// Wq[c,f,k] = W[(c*F3 + NN  + f)*KK + k]
// Wk[c,f,k] = W[(c*F3 + 0   + f)*KK + k]
__global__ __launch_bounds__(256) void k0_M(const float* __restrict__ W,
                                            float* __restrict__ M) {
  const int i = blockIdx.x >> 2, j = blockIdx.x & 3;
  __shared__ float wq[NN * KK];   // 32 KB
  __shared__ float wk[NN * KK];   // 32 KB
  const int baseq = (i * F3 + NN) * KK;
  const int basek = (j * F3) * KK;
  for (int idx = threadIdx.x; idx < NN * KK; idx += 256) {
    wq[idx] = W[baseq + idx];
    wk[idx] = W[basek + idx];
  }
  __syncthreads();
  const int k = threadIdx.x >> 4, k2 = threadIdx.x & 15;
  float acc = 0.f;
  for (int f = 0; f < NN; ++f)
    acc = fmaf(wq[f * KK + k], wk[f * KK + k2], acc);
  M[((i * 4 + j) * 16 + k) * 16 + k2] = acc;
}

// ---------------- k1: A[b][t][i][j] = 0.5*(softmax_j(w) + delta_ij) ---------
template <int I>
__device__ __forceinline__ void k1_row(const float xr[4][16],
                                       const float* __restrict__ M,
                                       float* __restrict__ A, int bb, int t) {
  float w[4];
#pragma unroll
  for (int j = 0; j < 4; ++j) {
    const float* Mp = M + (I * 4 + j) * 256;
    float acc = 0.f;
#pragma unroll
    for (int k = 0; k < 16; ++k) {
      float y = 0.f;
#pragma unroll
      for (int k2 = 0; k2 < 16; ++k2)
        y = fmaf(Mp[k * 16 + k2], xr[j][k2], y);
      acc = fmaf(xr[I][k], y, acc);
    }
    w[j] = acc;
  }
  const float m = fmaxf(fmaxf(w[0], w[1]), fmaxf(w[2], w[3]));
  const float e0 = __expf(w[0] - m), e1 = __expf(w[1] - m);
  const float e2 = __expf(w[2] - m), e3 = __expf(w[3] - m);
  const float inv = 0.5f / (e0 + e1 + e2 + e3);
  float4 av;
  av.x = e0 * inv;
  av.y = e1 * inv;
  av.z = e2 * inv;
  av.w = e3 * inv;
  if (I == 0) av.x += 0.5f;
  if (I == 1) av.y += 0.5f;
  if (I == 2) av.z += 0.5f;
  if (I == 3) av.w += 0.5f;
  // A[b][t][i][j], one float4 per (b,t,i)
  *reinterpret_cast<float4*>(A + ((bb * TT + t) * 4 + I) * 4) = av;
}

// block = 256 threads = 4 waves; each wave handles one query row i for the
// same 64 t values (uniform branch per wave, no divergence).
__global__ __launch_bounds__(256, 4) void k1_A(const float* __restrict__ x,
                                               const float* __restrict__ M,
                                               float* __restrict__ A) {
  const int bb = blockIdx.y;
  const int lane = threadIdx.x & 63;
  const int wv = threadIdx.x >> 6;
  const int t = blockIdx.x * 64 + lane;
  if (t >= TT) return;
  float xr[4][16];
#pragma unroll
  for (int c = 0; c < 4; ++c) {
    const float* xp = x + (bb * CC + c) * LL + t * ST;
#pragma unroll
    for (int k4 = 0; k4 < 16; k4 += 4) {
      const float4 v4 = *reinterpret_cast<const float4*>(xp + k4);
      xr[c][k4 + 0] = v4.x;
      xr[c][k4 + 1] = v4.y;
      xr[c][k4 + 2] = v4.z;
      xr[c][k4 + 3] = v4.w;
    }
  }
  if (wv == 0)      k1_row<0>(xr, M, A, bb, t);
  else if (wv == 1) k1_row<1>(xr, M, A, bb, t);
  else if (wv == 2) k1_row<2>(xr, M, A, bb, t);
  else              k1_row<3>(xr, M, A, bb, t);
}

// ---------------- k2: v-conv + mix + store ----------------------------------
// out[b,i,f,t] = sum_j A[b,t,i,j] * v[b,j,f,t],  v[c,f,t] = Wv[c,f,:] . x_c(t)
// Wv[c,f,k] = W[(c*F3 + 2*NN + f)*KK + k]   (wave-uniform index -> s_load)
// 1024-thread block covers 1024 consecutive t -> 4 KB contiguous store run
// per (i,f) row, issued as one temporally-clustered burst per f-iteration.
__global__ __launch_bounds__(1024, 4) void k2_out(const float* __restrict__ x,
                                                  const float* __restrict__ W,
                                                  const float* __restrict__ A,
                                                  float* __restrict__ out) {
  const int bb = blockIdx.x >> 2;
  const int t = (blockIdx.x & 3) * 1024 + (int)threadIdx.x;
  const int f0 = blockIdx.y * FC;
  if (t >= TT) return;
  float xr[4][16];
#pragma unroll
  for (int c = 0; c < 4; ++c) {
    const float* xp = x + (bb * CC + c) * LL + t * ST;
#pragma unroll
    for (int k4 = 0; k4 < 16; k4 += 4) {
      const float4 v4 = *reinterpret_cast<const float4*>(xp + k4);
      xr[c][k4 + 0] = v4.x;
      xr[c][k4 + 1] = v4.y;
      xr[c][k4 + 2] = v4.z;
      xr[c][k4 + 3] = v4.w;
    }
  }
  float4 a[4];
  {
    const float4* ap = reinterpret_cast<const float4*>(A + (bb * TT + t) * 16);
#pragma unroll
    for (int i = 0; i < 4; ++i) a[i] = ap[i];
  }

#pragma unroll 2
  for (int f = 0; f < FC; ++f) {
    const int fg = f0 + f;
    const float* w0 = W + (0 * F3 + 2 * NN + fg) * KK;
    const float* w1 = W + (1 * F3 + 2 * NN + fg) * KK;
    const float* w2 = W + (2 * F3 + 2 * NN + fg) * KK;
    const float* w3 = W + (3 * F3 + 2 * NN + fg) * KK;
    float v0 = 0.f, v1 = 0.f, v2 = 0.f, v3 = 0.f;
#pragma unroll
    for (int k = 0; k < 16; ++k) {
      v0 = fmaf(w0[k], xr[0][k], v0);
      v1 = fmaf(w1[k], xr[1][k], v1);
      v2 = fmaf(w2[k], xr[2][k], v2);
      v3 = fmaf(w3[k], xr[3][k], v3);
    }
#pragma unroll
    for (int i = 0; i < 4; ++i) {
      const float o =
          fmaf(a[i].w, v3, fmaf(a[i].z, v2, fmaf(a[i].y, v1, a[i].x * v0)));
      out[((bb * 4 + i) * NN + fg) * TT + t] = o;
    }
  }
}

extern "C" void kernel_launch(void* const* d_in, const int* in_sizes, int n_in,
                              void* d_out, int out_size, void* d_ws,
                              size_t ws_size, hipStream_t stream) {
  const float* x = (const float*)d_in[0];   // [B, C, L] fp32
  const float* W = (const float*)d_in[1];   // [C, F3, 1, K] fp32
  float* out = (float*)d_out;               // [B, C, N, T] fp32
  float* Mws = (float*)d_ws;                // 4096 floats
  float* Aws = Mws + 4 * 4 * 16 * 16;       // B*T*4*4 floats (~1 MB)

  hipLaunchKernelGGL(k0_M, dim3(16), dim3(256), 0, stream, W, Mws);
  hipLaunchKernelGGL(k1_A, dim3(63, BB), dim3(256), 0, stream, x, Mws, Aws);
  // 16 blocks.x = 4 b * 4 t-tiles (1024 t each); 16 blocks.y = 512/FC f-tiles
  hipLaunchKernelGGL(k2_out, dim3(16, 16), dim3(1024), 0, stream, x, W, Aws,
                     out);
}